// Round 14
// baseline (431.592 us; speedup 1.0000x reference)
//
#include <hip/hip_runtime.h>
#include <hip/hip_bf16.h>
#include <stdint.h>

// Problem constants
#define NB 8
#define NC 256
#define NN 16384
#define KS 64        // gram k-split: 64 chunks of 256 -> 512 blocks (2/CU)

typedef short bf16x8 __attribute__((ext_vector_type(8)));  // 8 bf16 = 4 VGPR
typedef float f32x4  __attribute__((ext_vector_type(4)));
typedef uint32_t u32;

__device__ __forceinline__ unsigned short f2bf(float f) {
  union { float f; unsigned u; } c; c.f = f;
  return (unsigned short)((c.u + 0x7FFFu + ((c.u >> 16) & 1u)) >> 16);  // RNE
}
__device__ __forceinline__ float bf2f(unsigned short h) {
  union { unsigned u; float f; } c; c.u = ((unsigned)h) << 16;
  return c.f;
}

// pack 8 f32 -> bf16x8 (RNE, same as f2bf)
__device__ __forceinline__ bf16x8 pack8(float4 lo, float4 hi) {
  union { bf16x8 v; __hip_bfloat162 h[4]; } u;
  u.h[0] = __float22bfloat162_rn(make_float2(lo.x, lo.y));
  u.h[1] = __float22bfloat162_rn(make_float2(lo.z, lo.w));
  u.h[2] = __float22bfloat162_rn(make_float2(hi.x, hi.y));
  u.h[3] = __float22bfloat162_rn(make_float2(hi.z, hi.w));
  return u.v;
}

// async global->LDS, 16B per lane; LDS dest is wave-uniform base + lane*16
__device__ __forceinline__ void gload16(const void* g, void* l) {
  __builtin_amdgcn_global_load_lds(
      (const __attribute__((address_space(1))) u32*)g,
      (__attribute__((address_space(3))) u32*)l, 16, 0, 0);
}

// Stage a [128 rows x 64 bf16] tile (row stride ld_bytes) into 16KB of LDS.
// T2 XOR-swizzle applied on the per-lane global source; LDS stays linear.
__device__ __forceinline__ void stage_tile(const char* src, int ld_bytes,
                                           char* lds, int w, int l) {
#pragma unroll
  for (int i = 0; i < 4; ++i) {
    int s = (w * 4 + i) * 64 + l;      // 0..1023 : 16B chunk index
    int row = s >> 3;
    int srcslot = (l & 7) ^ (row & 7);
    gload16(src + (size_t)row * ld_bytes + srcslot * 16,
            lds + (w * 4 + i) * 1024);
  }
}

// m97-style TN GEMM core: C[128,128] += A[128,K] * B[128,K]^T, K = ktiles*64.
__device__ __forceinline__ void gemm_core(const char* A, int lda_b,
                                          const char* Bm, int ldb_b, int ktiles,
                                          char* smem, int tid, f32x4 acc[4][4]) {
  const int w = tid >> 6, l = tid & 63;
  const int wm = w >> 1, wn = w & 1;
  char* As = smem;
  char* Bs = smem + 16384;
  for (int kt = 0; kt < ktiles; ++kt) {
    stage_tile(A + kt * 128, lda_b, As, w, l);
    stage_tile(Bm + kt * 128, ldb_b, Bs, w, l);
    __syncthreads();
#pragma unroll
    for (int ks = 0; ks < 2; ++ks) {
      bf16x8 av[4], bv[4];
      const int kb = ks * 64 + ((l >> 4) << 4);
#pragma unroll
      for (int m = 0; m < 4; ++m) {
        int row = wm * 64 + m * 16 + (l & 15);
        av[m] = *(const bf16x8*)(As + row * 128 + (kb ^ ((row & 7) << 4)));
      }
#pragma unroll
      for (int nq = 0; nq < 4; ++nq) {
        int row = wn * 64 + nq * 16 + (l & 15);
        bv[nq] = *(const bf16x8*)(Bs + row * 128 + (kb ^ ((row & 7) << 4)));
      }
#pragma unroll
      for (int m = 0; m < 4; ++m)
#pragma unroll
        for (int nq = 0; nq < 4; ++nq)
          acc[m][nq] = __builtin_amdgcn_mfma_f32_16x16x32_bf16(
              av[m], bv[nq], acc[m][nq], 0, 0, 0);
    }
    __syncthreads();
  }
}

// ---- scaled fp32 weights: Wcat ([Wq2;Wk2]), WkT, Wv2 -----------------------
__global__ __launch_bounds__(256) void k_prepw2(const float* __restrict__ wqkv,
                                                const float* __restrict__ wdw,
                                                float* __restrict__ Wcat,
                                                float* __restrict__ WkT,
                                                float* __restrict__ Wv2) {
  const int r = blockIdx.x, t = threadIdx.x;
  Wcat[r * 256 + t] = wqkv[r * 256 + t] * wdw[r];
  float kv = wqkv[(256 + r) * 256 + t] * wdw[256 + r];
  Wcat[65536 + r * 256 + t] = kv;
  WkT[t * 256 + r] = kv;
  Wv2[r * 256 + t] = wqkv[(512 + r) * 256 + t] * wdw[512 + r];
}

// ---- gramT v3: fused gram + transpose; KS=64 -> 512 blocks (2/CU), each
// with a DISJOINT K-chunk of 256 (4 ktiles of 64). No staging duplication;
// co-resident blocks overlap stage-drain with compute (m114 TLP).
// Per ktile: stage 256x64 fp32 (64KB single buffer, slot-swizzled), full
// 256x256 MFMA partial (8x4 acc/wave), xt transpose. gpart stored BF16.
__global__ __launch_bounds__(512, 4) void k_gramT(const float* __restrict__ x,
                                                  unsigned short* __restrict__ gpart,
                                                  char* __restrict__ xt) {
  __shared__ __align__(16) float tile[256 * 64];  // 64KB, single buffer
  const int tid = threadIdx.x;
  const int ks = blockIdx.x, b = blockIdx.y;
  const int w = tid >> 6, l = tid & 63;
  const int wm = w >> 2, wn = w & 3;     // 2m x 4n
  f32x4 acc[8][4];
#pragma unroll
  for (int m = 0; m < 8; ++m)
#pragma unroll
    for (int n = 0; n < 4; ++n) acc[m][n] = (f32x4){0.f, 0.f, 0.f, 0.f};
  const float* x0 = x + (size_t)b * NC * NN + (size_t)ks * 256;

  for (int kt = 0; kt < 4; ++kt) {
    // stage 256x64 fp32 (4096 16B chunks, 8/thread), source-swizzled
#pragma unroll
    for (int i = 0; i < 8; ++i) {
      int c = (w * 8 + i) * 64 + l;          // 0..4095 16B chunks
      int row = c >> 4, slot = c & 15;
      int sl = slot ^ (row & 15);
      gload16(x0 + (size_t)row * NN + kt * 64 + sl * 4,
              (char*)tile + (w * 8 + i) * 1024);
    }
    __syncthreads();
    // ---- gram MFMA ----
#pragma unroll
    for (int ks2 = 0; ks2 < 2; ++ks2) {
      const int s0 = ks2 * 8 + (l >> 4) * 2;  // logical 16B slot pair
      bf16x8 av[8], bv[4];
#pragma unroll
      for (int m = 0; m < 8; ++m) {
        int row = wm * 128 + m * 16 + (l & 15);
        float4 lo = *(const float4*)&tile[row * 64 + ((s0 ^ (row & 15)) * 4)];
        float4 hi = *(const float4*)&tile[row * 64 + (((s0 + 1) ^ (row & 15)) * 4)];
        av[m] = pack8(lo, hi);
      }
#pragma unroll
      for (int n = 0; n < 4; ++n) {
        int row = wn * 64 + n * 16 + (l & 15);
        float4 lo = *(const float4*)&tile[row * 64 + ((s0 ^ (row & 15)) * 4)];
        float4 hi = *(const float4*)&tile[row * 64 + (((s0 + 1) ^ (row & 15)) * 4)];
        bv[n] = pack8(lo, hi);
      }
#pragma unroll
      for (int m = 0; m < 8; ++m)
#pragma unroll
        for (int n = 0; n < 4; ++n)
          acc[m][n] = __builtin_amdgcn_mfma_f32_16x16x32_bf16(
              av[m], bv[n], acc[m][n], 0, 0, 0);
    }
    // ---- transpose-convert: xt[b][n][c] for this ktile ----
    {
      const int n4 = tid >> 5, c8 = tid & 31;   // n-quad 0..15, c-octet 0..31
      const int gn = ks * 256 + kt * 64 + n4 * 4;
      float vr[8][4];
#pragma unroll
      for (int j = 0; j < 8; ++j) {
        int c = c8 * 8 + j;
        float4 v = *(const float4*)&tile[c * 64 + ((n4 ^ (c & 15)) * 4)];
        vr[j][0] = v.x; vr[j][1] = v.y; vr[j][2] = v.z; vr[j][3] = v.w;
      }
#pragma unroll
      for (int k = 0; k < 4; ++k) {
        unsigned short ov[8] __attribute__((aligned(16)));
#pragma unroll
        for (int j = 0; j < 8; ++j) ov[j] = f2bf(vr[j][k]);
        *(uint4*)(xt + (((size_t)b * NN + gn + k) * 256 + c8 * 8) * 2) =
            *(const uint4*)(ov);
      }
    }
    __syncthreads();   // tile fully consumed; safe to overwrite next ktile
  }
  // ---- gpart epilogue (bf16) ----
  unsigned short* gp = gpart + ((size_t)(ks * NB + b)) * 65536;
#pragma unroll
  for (int m = 0; m < 8; ++m)
#pragma unroll
    for (int n = 0; n < 4; ++n)
#pragma unroll
      for (int r = 0; r < 4; ++r) {
        int c = wm * 128 + m * 16 + ((l >> 4) << 2) + r;
        int d = wn * 64 + n * 16 + (l & 15);
        gp[(size_t)c * 256 + d] = f2bf(acc[m][n][r]);
      }
}

// ---- G[b] = sum_ks gpart (bf16 in, fp32 out); grid (128, NB) ---------------
__global__ __launch_bounds__(256) void k_reduceG(
    const unsigned short* __restrict__ gpart, float* __restrict__ G) {
  const int t = threadIdx.x;
  const int c = blockIdx.x * 2 + (t >> 7), b = blockIdx.y;
  const int d0 = (t & 127) * 2;
  float s0 = 0.f, s1 = 0.f;
#pragma unroll 8
  for (int ks = 0; ks < KS; ++ks) {
    u32 v = *(const u32*)(gpart + (((size_t)ks * NB + b) * 256 + c) * 256 + d0);
    s0 += bf2f((unsigned short)(v & 0xffff));
    s1 += bf2f((unsigned short)(v >> 16));
  }
  *(float2*)(G + ((size_t)b * 256 + c) * 256 + d0) = make_float2(s0, s1);
}

// ---- T12 = Wcat @ G, fused with norms: nqk[b][r] = dot(T12[b][r], Wcat[r]) -
__global__ __launch_bounds__(256) void k_sgT(const float* __restrict__ Wcat,
                                             const float* __restrict__ G,
                                             float* __restrict__ T12,
                                             float* __restrict__ nqk) {
  const int t = threadIdx.x;
  const int r0 = blockIdx.x * 8, b = blockIdx.y;
  const float* Gb = G + (size_t)b * 65536 + t;
  float acc[8] = {0, 0, 0, 0, 0, 0, 0, 0};
#pragma unroll 4
  for (int k = 0; k < 256; ++k) {
    float bv = Gb[(size_t)k * 256];
#pragma unroll
    for (int o = 0; o < 8; ++o) acc[o] += Wcat[(r0 + o) * 256 + k] * bv;
  }
#pragma unroll
  for (int o = 0; o < 8; ++o)
    T12[(size_t)b * 131072 + (size_t)(r0 + o) * 256 + t] = acc[o];
  __shared__ float red[8][4];
  const int w = t >> 6, l = t & 63;
#pragma unroll
  for (int o = 0; o < 8; ++o) {
    float s = acc[o] * Wcat[(r0 + o) * 256 + t];
#pragma unroll
    for (int off = 32; off; off >>= 1) s += __shfl_xor(s, off);
    if (l == 0) red[o][w] = s;
  }
  __syncthreads();
  if (t < 8)
    nqk[b * 512 + r0 + t] = red[t][0] + red[t][1] + red[t][2] + red[t][3];
}

// ---- S = T1 @ Wk2^T fused with scaling + row-softmax -> attn ---------------
__global__ __launch_bounds__(256) void k_ssoft(const float* __restrict__ T12,
                                               const float* __restrict__ WkT,
                                               const float* __restrict__ nqk,
                                               const float* __restrict__ temp,
                                               float* __restrict__ attn) {
  const int t = threadIdx.x;
  const int c0 = blockIdx.x * 8, b = blockIdx.y;
  const float* Ab = T12 + (size_t)b * 131072 + (size_t)c0 * 256;  // T1 rows
  const float* Bb = WkT + t;
  float acc[8] = {0, 0, 0, 0, 0, 0, 0, 0};
#pragma unroll 4
  for (int k = 0; k < 256; ++k) {
    float bv = Bb[(size_t)k * 256];
#pragma unroll
    for (int o = 0; o < 8; ++o) acc[o] += Ab[o * 256 + k] * bv;
  }
  const float rk = 1.0f / fmaxf(sqrtf(fmaxf(nqk[b * 512 + 256 + t], 0.f)), 1e-12f);
  const float tau = temp[0];
#pragma unroll
  for (int o = 0; o < 8; ++o) {
    float rq = 1.0f / fmaxf(sqrtf(fmaxf(nqk[b * 512 + c0 + o], 0.f)), 1e-12f);
    acc[o] = acc[o] * rq * rk * tau;
  }
  __shared__ float redm[8][4];
  __shared__ float reds[8][4];
  const int w = t >> 6, l = t & 63;
#pragma unroll
  for (int o = 0; o < 8; ++o) {
    float m = acc[o];
#pragma unroll
    for (int off = 32; off; off >>= 1) m = fmaxf(m, __shfl_xor(m, off));
    if (l == 0) redm[o][w] = m;
  }
  __syncthreads();
  float e[8];
#pragma unroll
  for (int o = 0; o < 8; ++o) {
    float m = fmaxf(fmaxf(redm[o][0], redm[o][1]), fmaxf(redm[o][2], redm[o][3]));
    e[o] = __expf(acc[o] - m);
    float s = e[o];
#pragma unroll
    for (int off = 32; off; off >>= 1) s += __shfl_xor(s, off);
    if (l == 0) reds[o][w] = s;
  }
  __syncthreads();
#pragma unroll
  for (int o = 0; o < 8; ++o) {
    float tot = reds[o][0] + reds[o][1] + reds[o][2] + reds[o][3];
    attn[(size_t)b * 65536 + (size_t)(c0 + o) * 256 + t] = e[o] / tot;
  }
}

// ---- fused F = (Wp @ attn) @ Wv2, bf16 out ---------------------------------
__global__ __launch_bounds__(256) void k_sg2x(const float* __restrict__ wp,
                                              const float* __restrict__ attn,
                                              const float* __restrict__ wv2,
                                              char* __restrict__ Fb) {
  __shared__ float P[8 * 256];
  const int t = threadIdx.x;
  const int o0 = blockIdx.x * 8, b = blockIdx.y;
  const float* Ab = wp + (size_t)o0 * 256;
  const float* Bb = attn + (size_t)b * 65536 + t;
  float acc[8] = {0, 0, 0, 0, 0, 0, 0, 0};
#pragma unroll 4
  for (int k = 0; k < 256; ++k) {
    float bv = Bb[(size_t)k * 256];
#pragma unroll
    for (int o = 0; o < 8; ++o) acc[o] += Ab[o * 256 + k] * bv;
  }
#pragma unroll
  for (int o = 0; o < 8; ++o) P[o * 256 + t] = acc[o];
  __syncthreads();
  float a2[8] = {0, 0, 0, 0, 0, 0, 0, 0};
  const float* Bv = wv2 + t;
#pragma unroll 4
  for (int k = 0; k < 256; ++k) {
    float bv = Bv[(size_t)k * 256];
#pragma unroll
    for (int o = 0; o < 8; ++o) a2[o] += P[o * 256 + k] * bv;
  }
  unsigned short* Cp = (unsigned short*)Fb + (size_t)b * 65536;
#pragma unroll
  for (int o = 0; o < 8; ++o) Cp[(size_t)(o0 + o) * 256 + t] = f2bf(a2[o]);
}

// ---- final: out[b][o][n] = F[b] @ x[b] ; outT tiles (r4/r11 64KB version) --
__global__ __launch_bounds__(256) void k_final(const char* __restrict__ xt,
                                               const char* __restrict__ fb,
                                               float* __restrict__ out) {
  __shared__ char smem[65536];
  const int tid = threadIdx.x;
  const int nt = blockIdx.x, ot = blockIdx.y, b = blockIdx.z;
  f32x4 acc[4][4];
#pragma unroll
  for (int m = 0; m < 4; ++m)
#pragma unroll
    for (int nq = 0; nq < 4; ++nq) acc[m][nq] = (f32x4){0.f, 0.f, 0.f, 0.f};
  const char* Ap = xt + ((size_t)b * NN + (size_t)nt * 128) * 512;
  const char* Bp = fb + ((size_t)(b * 256 + ot * 128)) * 512;
  gemm_core(Ap, 512, Bp, 512, 4, smem, tid, acc);
  const int w = tid >> 6, l = tid & 63, wm = w >> 1, wn = w & 1;
#pragma unroll
  for (int m = 0; m < 4; ++m)
#pragma unroll
    for (int nq = 0; nq < 4; ++nq)
#pragma unroll
      for (int r = 0; r < 4; ++r) {
        int i = wm * 64 + m * 16 + ((l >> 4) << 2) + r;  // n_local (A row)
        int j = wn * 64 + nq * 16 + (l & 15);            // o_local (B row)
        *(float*)(smem + j * 512 + ((i * 4) ^ ((j & 7) << 4))) = acc[m][nq][r];
      }
  __syncthreads();
  const int j = tid >> 1, h = tid & 1;
  float* dst = out + ((size_t)(b * 256 + ot * 128 + j)) * NN + nt * 128;
#pragma unroll
  for (int cc = 0; cc < 16; ++cc) {
    int ch = h * 16 + cc;
    *(uint4*)(dst + ch * 4) =
        *(const uint4*)(smem + j * 512 + ((ch * 16) ^ ((j & 7) << 4)));
  }
}

extern "C" void kernel_launch(void* const* d_in, const int* in_sizes, int n_in,
                              void* d_out, int out_size, void* d_ws, size_t ws_size,
                              hipStream_t stream) {
  const float* x     = (const float*)d_in[0];
  const float* wqkv  = (const float*)d_in[1];
  const float* wdwf  = (const float*)d_in[2];
  const float* temp  = (const float*)d_in[3];
  const float* wproj = (const float*)d_in[4];
  float* out = (float*)d_out;
  char* ws = (char*)d_ws;

  // Workspace layout (bytes); total ~145 MB
  char*  xt    = ws;                            // bf16 [B][N][C]      67,108,864
  unsigned short* gpart = (unsigned short*)(ws + 67108864);
                                                // bf16 [64][B][256][256] 67,108,864
  float* G     = (float*)(ws + 134217728);      // f32 [B][256][256]    2,097,152
  float* T12   = (float*)(ws + 136314880);      // f32 [B][512][256]    4,194,304
  float* attn  = (float*)(ws + 140509184);      // f32 [B][256][256]    2,097,152
  char*  Fb    = ws + 142606336;                // bf16 [B][256][256]   1,048,576
  float* Wcat  = (float*)(ws + 143654912);      // f32 [512][256]         524,288
  float* WkT   = (float*)(ws + 144179200);      // f32 [256][256]         262,144
  float* Wv2   = (float*)(ws + 144441344);      // f32 [256][256]         262,144
  float* nqk   = (float*)(ws + 144703488);      // f32 [B][512]            16,384

  k_prepw2<<<dim3(256), dim3(256), 0, stream>>>(wqkv, wdwf, Wcat, WkT, Wv2);
  // fused gram + transpose-convert: 512 blocks (2/CU), disjoint K-chunks
  k_gramT<<<dim3(KS, NB), dim3(512), 0, stream>>>(x, gpart, xt);
  k_reduceG<<<dim3(128, NB), dim3(256), 0, stream>>>(gpart, G);
  k_sgT<<<dim3(64, NB), dim3(256), 0, stream>>>(Wcat, G, T12, nqk);
  k_ssoft<<<dim3(32, NB), dim3(256), 0, stream>>>(T12, WkT, nqk, temp, attn);
  k_sg2x<<<dim3(32, NB), dim3(256), 0, stream>>>(wproj, attn, Wv2, Fb);
  k_final<<<dim3(128, 2, NB), dim3(256), 0, stream>>>(xt, Fb, out);
}

// Round 15
// 247.037 us; speedup vs baseline: 1.7471x; 1.7471x over previous
//
#include <hip/hip_runtime.h>
#include <hip/hip_bf16.h>
#include <stdint.h>

// Problem constants
#define NB 8
#define NC 256
#define NN 16384
#define KS 64        // gram k-split: 64 chunks of 256 -> 512 blocks (2/CU)

typedef short bf16x8 __attribute__((ext_vector_type(8)));  // 8 bf16 = 4 VGPR
typedef float f32x4  __attribute__((ext_vector_type(4)));
typedef uint32_t u32;

__device__ __forceinline__ unsigned short f2bf(float f) {
  union { float f; unsigned u; } c; c.f = f;
  return (unsigned short)((c.u + 0x7FFFu + ((c.u >> 16) & 1u)) >> 16);  // RNE
}
__device__ __forceinline__ float bf2f(unsigned short h) {
  union { unsigned u; float f; } c; c.u = ((unsigned)h) << 16;
  return c.f;
}

// pack 8 f32 -> bf16x8 (RNE, same as f2bf)
__device__ __forceinline__ bf16x8 pack8(float4 lo, float4 hi) {
  union { bf16x8 v; __hip_bfloat162 h[4]; } u;
  u.h[0] = __float22bfloat162_rn(make_float2(lo.x, lo.y));
  u.h[1] = __float22bfloat162_rn(make_float2(lo.z, lo.w));
  u.h[2] = __float22bfloat162_rn(make_float2(hi.x, hi.y));
  u.h[3] = __float22bfloat162_rn(make_float2(hi.z, hi.w));
  return u.v;
}

// async global->LDS, 16B per lane; LDS dest is wave-uniform base + lane*16
__device__ __forceinline__ void gload16(const void* g, void* l) {
  __builtin_amdgcn_global_load_lds(
      (const __attribute__((address_space(1))) u32*)g,
      (__attribute__((address_space(3))) u32*)l, 16, 0, 0);
}

// Stage a [128 rows x 64 bf16] tile (row stride ld_bytes) into 16KB of LDS.
// T2 XOR-swizzle applied on the per-lane global source; LDS stays linear.
__device__ __forceinline__ void stage_tile(const char* src, int ld_bytes,
                                           char* lds, int w, int l) {
#pragma unroll
  for (int i = 0; i < 4; ++i) {
    int s = (w * 4 + i) * 64 + l;      // 0..1023 : 16B chunk index
    int row = s >> 3;
    int srcslot = (l & 7) ^ (row & 7);
    gload16(src + (size_t)row * ld_bytes + srcslot * 16,
            lds + (w * 4 + i) * 1024);
  }
}

// m97-style TN GEMM core: C[128,128] += A[128,K] * B[128,K]^T, K = ktiles*64.
__device__ __forceinline__ void gemm_core(const char* A, int lda_b,
                                          const char* Bm, int ldb_b, int ktiles,
                                          char* smem, int tid, f32x4 acc[4][4]) {
  const int w = tid >> 6, l = tid & 63;
  const int wm = w >> 1, wn = w & 1;
  char* As = smem;
  char* Bs = smem + 16384;
  for (int kt = 0; kt < ktiles; ++kt) {
    stage_tile(A + kt * 128, lda_b, As, w, l);
    stage_tile(Bm + kt * 128, ldb_b, Bs, w, l);
    __syncthreads();
#pragma unroll
    for (int ks = 0; ks < 2; ++ks) {
      bf16x8 av[4], bv[4];
      const int kb = ks * 64 + ((l >> 4) << 4);
#pragma unroll
      for (int m = 0; m < 4; ++m) {
        int row = wm * 64 + m * 16 + (l & 15);
        av[m] = *(const bf16x8*)(As + row * 128 + (kb ^ ((row & 7) << 4)));
      }
#pragma unroll
      for (int nq = 0; nq < 4; ++nq) {
        int row = wn * 64 + nq * 16 + (l & 15);
        bv[nq] = *(const bf16x8*)(Bs + row * 128 + (kb ^ ((row & 7) << 4)));
      }
#pragma unroll
      for (int m = 0; m < 4; ++m)
#pragma unroll
        for (int nq = 0; nq < 4; ++nq)
          acc[m][nq] = __builtin_amdgcn_mfma_f32_16x16x32_bf16(
              av[m], bv[nq], acc[m][nq], 0, 0, 0);
    }
    __syncthreads();
  }
}

// ---- scaled fp32 weights: Wcat ([Wq2;Wk2]), WkT, Wv2 -----------------------
__global__ __launch_bounds__(256) void k_prepw2(const float* __restrict__ wqkv,
                                                const float* __restrict__ wdw,
                                                float* __restrict__ Wcat,
                                                float* __restrict__ WkT,
                                                float* __restrict__ Wv2) {
  const int r = blockIdx.x, t = threadIdx.x;
  Wcat[r * 256 + t] = wqkv[r * 256 + t] * wdw[r];
  float kv = wqkv[(256 + r) * 256 + t] * wdw[256 + r];
  Wcat[65536 + r * 256 + t] = kv;
  WkT[t * 256 + r] = kv;
  Wv2[r * 256 + t] = wqkv[(512 + r) * 256 + t] * wdw[512 + r];
}

// ---- gramT v3b: fused gram + transpose; KS=64 -> 512 blocks (2/CU), each
// with a DISJOINT K-chunk of 256 (4 ktiles of 64). launch_bounds(512,2):
// VGPR ~116 (r12-measured) <= 128 so HW can co-schedule 2 blocks/CU —
// r14's (512,4) forced VGPR=64 and spilled catastrophically.
__global__ __launch_bounds__(512, 2) void k_gramT(const float* __restrict__ x,
                                                  unsigned short* __restrict__ gpart,
                                                  char* __restrict__ xt) {
  __shared__ __align__(16) float tile[256 * 64];  // 64KB, single buffer
  const int tid = threadIdx.x;
  const int ks = blockIdx.x, b = blockIdx.y;
  const int w = tid >> 6, l = tid & 63;
  const int wm = w >> 2, wn = w & 3;     // 2m x 4n
  f32x4 acc[8][4];
#pragma unroll
  for (int m = 0; m < 8; ++m)
#pragma unroll
    for (int n = 0; n < 4; ++n) acc[m][n] = (f32x4){0.f, 0.f, 0.f, 0.f};
  const float* x0 = x + (size_t)b * NC * NN + (size_t)ks * 256;

  for (int kt = 0; kt < 4; ++kt) {
    // stage 256x64 fp32 (4096 16B chunks, 8/thread), source-swizzled
#pragma unroll
    for (int i = 0; i < 8; ++i) {
      int c = (w * 8 + i) * 64 + l;          // 0..4095 16B chunks
      int row = c >> 4, slot = c & 15;
      int sl = slot ^ (row & 15);
      gload16(x0 + (size_t)row * NN + kt * 64 + sl * 4,
              (char*)tile + (w * 8 + i) * 1024);
    }
    __syncthreads();
    // ---- gram MFMA ----
#pragma unroll
    for (int ks2 = 0; ks2 < 2; ++ks2) {
      const int s0 = ks2 * 8 + (l >> 4) * 2;  // logical 16B slot pair
      bf16x8 av[8], bv[4];
#pragma unroll
      for (int m = 0; m < 8; ++m) {
        int row = wm * 128 + m * 16 + (l & 15);
        float4 lo = *(const float4*)&tile[row * 64 + ((s0 ^ (row & 15)) * 4)];
        float4 hi = *(const float4*)&tile[row * 64 + (((s0 + 1) ^ (row & 15)) * 4)];
        av[m] = pack8(lo, hi);
      }
#pragma unroll
      for (int n = 0; n < 4; ++n) {
        int row = wn * 64 + n * 16 + (l & 15);
        float4 lo = *(const float4*)&tile[row * 64 + ((s0 ^ (row & 15)) * 4)];
        float4 hi = *(const float4*)&tile[row * 64 + (((s0 + 1) ^ (row & 15)) * 4)];
        bv[n] = pack8(lo, hi);
      }
#pragma unroll
      for (int m = 0; m < 8; ++m)
#pragma unroll
        for (int n = 0; n < 4; ++n)
          acc[m][n] = __builtin_amdgcn_mfma_f32_16x16x32_bf16(
              av[m], bv[n], acc[m][n], 0, 0, 0);
    }
    // ---- transpose-convert: xt[b][n][c] for this ktile ----
    {
      const int n4 = tid >> 5, c8 = tid & 31;   // n-quad 0..15, c-octet 0..31
      const int gn = ks * 256 + kt * 64 + n4 * 4;
      float vr[8][4];
#pragma unroll
      for (int j = 0; j < 8; ++j) {
        int c = c8 * 8 + j;
        float4 v = *(const float4*)&tile[c * 64 + ((n4 ^ (c & 15)) * 4)];
        vr[j][0] = v.x; vr[j][1] = v.y; vr[j][2] = v.z; vr[j][3] = v.w;
      }
#pragma unroll
      for (int k = 0; k < 4; ++k) {
        unsigned short ov[8] __attribute__((aligned(16)));
#pragma unroll
        for (int j = 0; j < 8; ++j) ov[j] = f2bf(vr[j][k]);
        *(uint4*)(xt + (((size_t)b * NN + gn + k) * 256 + c8 * 8) * 2) =
            *(const uint4*)(ov);
      }
    }
    __syncthreads();   // tile fully consumed; safe to overwrite next ktile
  }
  // ---- gpart epilogue (bf16) ----
  unsigned short* gp = gpart + ((size_t)(ks * NB + b)) * 65536;
#pragma unroll
  for (int m = 0; m < 8; ++m)
#pragma unroll
    for (int n = 0; n < 4; ++n)
#pragma unroll
      for (int r = 0; r < 4; ++r) {
        int c = wm * 128 + m * 16 + ((l >> 4) << 2) + r;
        int d = wn * 64 + n * 16 + (l & 15);
        gp[(size_t)c * 256 + d] = f2bf(acc[m][n][r]);
      }
}

// ---- G[b] = sum_ks gpart (bf16 in, fp32 out); grid (128, NB) ---------------
__global__ __launch_bounds__(256) void k_reduceG(
    const unsigned short* __restrict__ gpart, float* __restrict__ G) {
  const int t = threadIdx.x;
  const int c = blockIdx.x * 2 + (t >> 7), b = blockIdx.y;
  const int d0 = (t & 127) * 2;
  float s0 = 0.f, s1 = 0.f;
#pragma unroll 8
  for (int ks = 0; ks < KS; ++ks) {
    u32 v = *(const u32*)(gpart + (((size_t)ks * NB + b) * 256 + c) * 256 + d0);
    s0 += bf2f((unsigned short)(v & 0xffff));
    s1 += bf2f((unsigned short)(v >> 16));
  }
  *(float2*)(G + ((size_t)b * 256 + c) * 256 + d0) = make_float2(s0, s1);
}

// ---- T12 = Wcat @ G, fused with norms: nqk[b][r] = dot(T12[b][r], Wcat[r]) -
__global__ __launch_bounds__(256) void k_sgT(const float* __restrict__ Wcat,
                                             const float* __restrict__ G,
                                             float* __restrict__ T12,
                                             float* __restrict__ nqk) {
  const int t = threadIdx.x;
  const int r0 = blockIdx.x * 8, b = blockIdx.y;
  const float* Gb = G + (size_t)b * 65536 + t;
  float acc[8] = {0, 0, 0, 0, 0, 0, 0, 0};
#pragma unroll 4
  for (int k = 0; k < 256; ++k) {
    float bv = Gb[(size_t)k * 256];
#pragma unroll
    for (int o = 0; o < 8; ++o) acc[o] += Wcat[(r0 + o) * 256 + k] * bv;
  }
#pragma unroll
  for (int o = 0; o < 8; ++o)
    T12[(size_t)b * 131072 + (size_t)(r0 + o) * 256 + t] = acc[o];
  __shared__ float red[8][4];
  const int w = t >> 6, l = t & 63;
#pragma unroll
  for (int o = 0; o < 8; ++o) {
    float s = acc[o] * Wcat[(r0 + o) * 256 + t];
#pragma unroll
    for (int off = 32; off; off >>= 1) s += __shfl_xor(s, off);
    if (l == 0) red[o][w] = s;
  }
  __syncthreads();
  if (t < 8)
    nqk[b * 512 + r0 + t] = red[t][0] + red[t][1] + red[t][2] + red[t][3];
}

// ---- S = T1 @ Wk2^T fused with scaling + row-softmax -> attn ---------------
__global__ __launch_bounds__(256) void k_ssoft(const float* __restrict__ T12,
                                               const float* __restrict__ WkT,
                                               const float* __restrict__ nqk,
                                               const float* __restrict__ temp,
                                               float* __restrict__ attn) {
  const int t = threadIdx.x;
  const int c0 = blockIdx.x * 8, b = blockIdx.y;
  const float* Ab = T12 + (size_t)b * 131072 + (size_t)c0 * 256;  // T1 rows
  const float* Bb = WkT + t;
  float acc[8] = {0, 0, 0, 0, 0, 0, 0, 0};
#pragma unroll 4
  for (int k = 0; k < 256; ++k) {
    float bv = Bb[(size_t)k * 256];
#pragma unroll
    for (int o = 0; o < 8; ++o) acc[o] += Ab[o * 256 + k] * bv;
  }
  const float rk = 1.0f / fmaxf(sqrtf(fmaxf(nqk[b * 512 + 256 + t], 0.f)), 1e-12f);
  const float tau = temp[0];
#pragma unroll
  for (int o = 0; o < 8; ++o) {
    float rq = 1.0f / fmaxf(sqrtf(fmaxf(nqk[b * 512 + c0 + o], 0.f)), 1e-12f);
    acc[o] = acc[o] * rq * rk * tau;
  }
  __shared__ float redm[8][4];
  __shared__ float reds[8][4];
  const int w = t >> 6, l = t & 63;
#pragma unroll
  for (int o = 0; o < 8; ++o) {
    float m = acc[o];
#pragma unroll
    for (int off = 32; off; off >>= 1) m = fmaxf(m, __shfl_xor(m, off));
    if (l == 0) redm[o][w] = m;
  }
  __syncthreads();
  float e[8];
#pragma unroll
  for (int o = 0; o < 8; ++o) {
    float m = fmaxf(fmaxf(redm[o][0], redm[o][1]), fmaxf(redm[o][2], redm[o][3]));
    e[o] = __expf(acc[o] - m);
    float s = e[o];
#pragma unroll
    for (int off = 32; off; off >>= 1) s += __shfl_xor(s, off);
    if (l == 0) reds[o][w] = s;
  }
  __syncthreads();
#pragma unroll
  for (int o = 0; o < 8; ++o) {
    float tot = reds[o][0] + reds[o][1] + reds[o][2] + reds[o][3];
    attn[(size_t)b * 65536 + (size_t)(c0 + o) * 256 + t] = e[o] / tot;
  }
}

// ---- fused F = (Wp @ attn) @ Wv2, bf16 out ---------------------------------
__global__ __launch_bounds__(256) void k_sg2x(const float* __restrict__ wp,
                                              const float* __restrict__ attn,
                                              const float* __restrict__ wv2,
                                              char* __restrict__ Fb) {
  __shared__ float P[8 * 256];
  const int t = threadIdx.x;
  const int o0 = blockIdx.x * 8, b = blockIdx.y;
  const float* Ab = wp + (size_t)o0 * 256;
  const float* Bb = attn + (size_t)b * 65536 + t;
  float acc[8] = {0, 0, 0, 0, 0, 0, 0, 0};
#pragma unroll 4
  for (int k = 0; k < 256; ++k) {
    float bv = Bb[(size_t)k * 256];
#pragma unroll
    for (int o = 0; o < 8; ++o) acc[o] += Ab[o * 256 + k] * bv;
  }
#pragma unroll
  for (int o = 0; o < 8; ++o) P[o * 256 + t] = acc[o];
  __syncthreads();
  float a2[8] = {0, 0, 0, 0, 0, 0, 0, 0};
  const float* Bv = wv2 + t;
#pragma unroll 4
  for (int k = 0; k < 256; ++k) {
    float bv = Bv[(size_t)k * 256];
#pragma unroll
    for (int o = 0; o < 8; ++o) a2[o] += P[o * 256 + k] * bv;
  }
  unsigned short* Cp = (unsigned short*)Fb + (size_t)b * 65536;
#pragma unroll
  for (int o = 0; o < 8; ++o) Cp[(size_t)(o0 + o) * 256 + t] = f2bf(a2[o]);
}

// ---- final: out[b][o][n] = F[b] @ x[b] ; outT tiles (r4/r11 64KB version) --
__global__ __launch_bounds__(256) void k_final(const char* __restrict__ xt,
                                               const char* __restrict__ fb,
                                               float* __restrict__ out) {
  __shared__ char smem[65536];
  const int tid = threadIdx.x;
  const int nt = blockIdx.x, ot = blockIdx.y, b = blockIdx.z;
  f32x4 acc[4][4];
#pragma unroll
  for (int m = 0; m < 4; ++m)
#pragma unroll
    for (int nq = 0; nq < 4; ++nq) acc[m][nq] = (f32x4){0.f, 0.f, 0.f, 0.f};
  const char* Ap = xt + ((size_t)b * NN + (size_t)nt * 128) * 512;
  const char* Bp = fb + ((size_t)(b * 256 + ot * 128)) * 512;
  gemm_core(Ap, 512, Bp, 512, 4, smem, tid, acc);
  const int w = tid >> 6, l = tid & 63, wm = w >> 1, wn = w & 1;
#pragma unroll
  for (int m = 0; m < 4; ++m)
#pragma unroll
    for (int nq = 0; nq < 4; ++nq)
#pragma unroll
      for (int r = 0; r < 4; ++r) {
        int i = wm * 64 + m * 16 + ((l >> 4) << 2) + r;  // n_local (A row)
        int j = wn * 64 + nq * 16 + (l & 15);            // o_local (B row)
        *(float*)(smem + j * 512 + ((i * 4) ^ ((j & 7) << 4))) = acc[m][nq][r];
      }
  __syncthreads();
  const int j = tid >> 1, h = tid & 1;
  float* dst = out + ((size_t)(b * 256 + ot * 128 + j)) * NN + nt * 128;
#pragma unroll
  for (int cc = 0; cc < 16; ++cc) {
    int ch = h * 16 + cc;
    *(uint4*)(dst + ch * 4) =
        *(const uint4*)(smem + j * 512 + ((ch * 16) ^ ((j & 7) << 4)));
  }
}

extern "C" void kernel_launch(void* const* d_in, const int* in_sizes, int n_in,
                              void* d_out, int out_size, void* d_ws, size_t ws_size,
                              hipStream_t stream) {
  const float* x     = (const float*)d_in[0];
  const float* wqkv  = (const float*)d_in[1];
  const float* wdwf  = (const float*)d_in[2];
  const float* temp  = (const float*)d_in[3];
  const float* wproj = (const float*)d_in[4];
  float* out = (float*)d_out;
  char* ws = (char*)d_ws;

  // Workspace layout (bytes); total ~145 MB
  char*  xt    = ws;                            // bf16 [B][N][C]      67,108,864
  unsigned short* gpart = (unsigned short*)(ws + 67108864);
                                                // bf16 [64][B][256][256] 67,108,864
  float* G     = (float*)(ws + 134217728);      // f32 [B][256][256]    2,097,152
  float* T12   = (float*)(ws + 136314880);      // f32 [B][512][256]    4,194,304
  float* attn  = (float*)(ws + 140509184);      // f32 [B][256][256]    2,097,152
  char*  Fb    = ws + 142606336;                // bf16 [B][256][256]   1,048,576
  float* Wcat  = (float*)(ws + 143654912);      // f32 [512][256]         524,288
  float* WkT   = (float*)(ws + 144179200);      // f32 [256][256]         262,144
  float* Wv2   = (float*)(ws + 144441344);      // f32 [256][256]         262,144
  float* nqk   = (float*)(ws + 144703488);      // f32 [B][512]            16,384

  k_prepw2<<<dim3(256), dim3(256), 0, stream>>>(wqkv, wdwf, Wcat, WkT, Wv2);
  // fused gram + transpose-convert: 512 blocks (2/CU), disjoint K-chunks
  k_gramT<<<dim3(KS, NB), dim3(512), 0, stream>>>(x, gpart, xt);
  k_reduceG<<<dim3(128, NB), dim3(256), 0, stream>>>(gpart, G);
  k_sgT<<<dim3(64, NB), dim3(256), 0, stream>>>(Wcat, G, T12, nqk);
  k_ssoft<<<dim3(32, NB), dim3(256), 0, stream>>>(T12, WkT, nqk, temp, attn);
  k_sg2x<<<dim3(32, NB), dim3(256), 0, stream>>>(wproj, attn, Wv2, Fb);
  k_final<<<dim3(128, 2, NB), dim3(256), 0, stream>>>(xt, Fb, out);
}

// Round 16
// 246.448 us; speedup vs baseline: 1.7512x; 1.0024x over previous
//
#include <hip/hip_runtime.h>
#include <hip/hip_bf16.h>
#include <stdint.h>

// Problem constants
#define NB 8
#define NC 256
#define NN 16384
#define KS 64        // gram k-split: 64 chunks of 256 -> 512 blocks (2/CU)

typedef short bf16x8 __attribute__((ext_vector_type(8)));  // 8 bf16 = 4 VGPR
typedef float f32x4  __attribute__((ext_vector_type(4)));
typedef uint32_t u32;

__device__ __forceinline__ unsigned short f2bf(float f) {
  union { float f; unsigned u; } c; c.f = f;
  return (unsigned short)((c.u + 0x7FFFu + ((c.u >> 16) & 1u)) >> 16);  // RNE
}
__device__ __forceinline__ float bf2f(unsigned short h) {
  union { unsigned u; float f; } c; c.u = ((unsigned)h) << 16;
  return c.f;
}

// pack 8 f32 -> bf16x8 (RNE, same as f2bf)
__device__ __forceinline__ bf16x8 pack8(float4 lo, float4 hi) {
  union { bf16x8 v; __hip_bfloat162 h[4]; } u;
  u.h[0] = __float22bfloat162_rn(make_float2(lo.x, lo.y));
  u.h[1] = __float22bfloat162_rn(make_float2(lo.z, lo.w));
  u.h[2] = __float22bfloat162_rn(make_float2(hi.x, hi.y));
  u.h[3] = __float22bfloat162_rn(make_float2(hi.z, hi.w));
  return u.v;
}

// async global->LDS, 16B per lane; LDS dest is wave-uniform base + lane*16
__device__ __forceinline__ void gload16(const void* g, void* l) {
  __builtin_amdgcn_global_load_lds(
      (const __attribute__((address_space(1))) u32*)g,
      (__attribute__((address_space(3))) u32*)l, 16, 0, 0);
}

// Stage a [128 rows x 64 bf16] tile (row stride ld_bytes) into 16KB of LDS.
// T2 XOR-swizzle applied on the per-lane global source; LDS stays linear.
__device__ __forceinline__ void stage_tile(const char* src, int ld_bytes,
                                           char* lds, int w, int l) {
#pragma unroll
  for (int i = 0; i < 4; ++i) {
    int s = (w * 4 + i) * 64 + l;      // 0..1023 : 16B chunk index
    int row = s >> 3;
    int srcslot = (l & 7) ^ (row & 7);
    gload16(src + (size_t)row * ld_bytes + srcslot * 16,
            lds + (w * 4 + i) * 1024);
  }
}

// ---- gramT + prepw merged (role-split blocks, r9 pattern) ------------------
// blocks [0,512): fused gram + transpose-convert, disjoint K-chunks of 256.
// blocks [512,640): scaled-weight prep (2 rows per 512-thread block).
__global__ __launch_bounds__(512, 2) void k_gramT(
    const float* __restrict__ x, unsigned short* __restrict__ gpart,
    char* __restrict__ xt,
    const float* __restrict__ wqkv, const float* __restrict__ wdw,
    float* __restrict__ Wcat, float* __restrict__ WkT,
    float* __restrict__ Wv2) {
  __shared__ __align__(16) float tile[256 * 64];  // 64KB, single buffer
  const int bid = blockIdx.x;
  const int tid = threadIdx.x;

  if (bid >= KS * NB) {
    // ---------------- prepw role ----------------
    const int r = (bid - KS * NB) * 2 + (tid >> 8);
    const int t = tid & 255;
    Wcat[r * 256 + t] = wqkv[r * 256 + t] * wdw[r];
    float kv = wqkv[(256 + r) * 256 + t] * wdw[256 + r];
    Wcat[65536 + r * 256 + t] = kv;
    WkT[t * 256 + r] = kv;
    Wv2[r * 256 + t] = wqkv[(512 + r) * 256 + t] * wdw[512 + r];
    return;
  }

  // ---------------- gram role ----------------
  const int ks = bid & (KS - 1), b = bid >> 6;
  const int w = tid >> 6, l = tid & 63;
  const int wm = w >> 2, wn = w & 3;     // 2m x 4n
  f32x4 acc[8][4];
#pragma unroll
  for (int m = 0; m < 8; ++m)
#pragma unroll
    for (int n = 0; n < 4; ++n) acc[m][n] = (f32x4){0.f, 0.f, 0.f, 0.f};
  const float* x0 = x + (size_t)b * NC * NN + (size_t)ks * 256;

  for (int kt = 0; kt < 4; ++kt) {
    // stage 256x64 fp32 (4096 16B chunks, 8/thread), source-swizzled
#pragma unroll
    for (int i = 0; i < 8; ++i) {
      int c = (w * 8 + i) * 64 + l;          // 0..4095 16B chunks
      int row = c >> 4, slot = c & 15;
      int sl = slot ^ (row & 15);
      gload16(x0 + (size_t)row * NN + kt * 64 + sl * 4,
              (char*)tile + (w * 8 + i) * 1024);
    }
    __syncthreads();
    // ---- gram MFMA ----
#pragma unroll
    for (int ks2 = 0; ks2 < 2; ++ks2) {
      const int s0 = ks2 * 8 + (l >> 4) * 2;  // logical 16B slot pair
      bf16x8 av[8], bv[4];
#pragma unroll
      for (int m = 0; m < 8; ++m) {
        int row = wm * 128 + m * 16 + (l & 15);
        float4 lo = *(const float4*)&tile[row * 64 + ((s0 ^ (row & 15)) * 4)];
        float4 hi = *(const float4*)&tile[row * 64 + (((s0 + 1) ^ (row & 15)) * 4)];
        av[m] = pack8(lo, hi);
      }
#pragma unroll
      for (int n = 0; n < 4; ++n) {
        int row = wn * 64 + n * 16 + (l & 15);
        float4 lo = *(const float4*)&tile[row * 64 + ((s0 ^ (row & 15)) * 4)];
        float4 hi = *(const float4*)&tile[row * 64 + (((s0 + 1) ^ (row & 15)) * 4)];
        bv[n] = pack8(lo, hi);
      }
#pragma unroll
      for (int m = 0; m < 8; ++m)
#pragma unroll
        for (int n = 0; n < 4; ++n)
          acc[m][n] = __builtin_amdgcn_mfma_f32_16x16x32_bf16(
              av[m], bv[n], acc[m][n], 0, 0, 0);
    }
    // ---- transpose-convert: xt[b][n][c] for this ktile ----
    {
      const int n4 = tid >> 5, c8 = tid & 31;   // n-quad 0..15, c-octet 0..31
      const int gn = ks * 256 + kt * 64 + n4 * 4;
      float vr[8][4];
#pragma unroll
      for (int j = 0; j < 8; ++j) {
        int c = c8 * 8 + j;
        float4 v = *(const float4*)&tile[c * 64 + ((n4 ^ (c & 15)) * 4)];
        vr[j][0] = v.x; vr[j][1] = v.y; vr[j][2] = v.z; vr[j][3] = v.w;
      }
#pragma unroll
      for (int k = 0; k < 4; ++k) {
        unsigned short ov[8] __attribute__((aligned(16)));
#pragma unroll
        for (int j = 0; j < 8; ++j) ov[j] = f2bf(vr[j][k]);
        *(uint4*)(xt + (((size_t)b * NN + gn + k) * 256 + c8 * 8) * 2) =
            *(const uint4*)(ov);
      }
    }
    __syncthreads();   // tile fully consumed; safe to overwrite next ktile
  }
  // ---- gpart epilogue (bf16) ----
  unsigned short* gp = gpart + ((size_t)(ks * NB + b)) * 65536;
#pragma unroll
  for (int m = 0; m < 8; ++m)
#pragma unroll
    for (int n = 0; n < 4; ++n)
#pragma unroll
      for (int r = 0; r < 4; ++r) {
        int c = wm * 128 + m * 16 + ((l >> 4) << 2) + r;
        int d = wn * 64 + n * 16 + (l & 15);
        gp[(size_t)c * 256 + d] = f2bf(acc[m][n][r]);
      }
}

// ---- G[b] = sum_ks gpart (bf16 in, fp32 out); grid (128, NB) ---------------
__global__ __launch_bounds__(256) void k_reduceG(
    const unsigned short* __restrict__ gpart, float* __restrict__ G) {
  const int t = threadIdx.x;
  const int c = blockIdx.x * 2 + (t >> 7), b = blockIdx.y;
  const int d0 = (t & 127) * 2;
  float s0 = 0.f, s1 = 0.f;
#pragma unroll 8
  for (int ks = 0; ks < KS; ++ks) {
    u32 v = *(const u32*)(gpart + (((size_t)ks * NB + b) * 256 + c) * 256 + d0);
    s0 += bf2f((unsigned short)(v & 0xffff));
    s1 += bf2f((unsigned short)(v >> 16));
  }
  *(float2*)(G + ((size_t)b * 256 + c) * 256 + d0) = make_float2(s0, s1);
}

// ---- T12 = Wcat @ G, fused with norms: nqk[b][r] = dot(T12[b][r], Wcat[r]) -
__global__ __launch_bounds__(256) void k_sgT(const float* __restrict__ Wcat,
                                             const float* __restrict__ G,
                                             float* __restrict__ T12,
                                             float* __restrict__ nqk) {
  const int t = threadIdx.x;
  const int r0 = blockIdx.x * 8, b = blockIdx.y;
  const float* Gb = G + (size_t)b * 65536 + t;
  float acc[8] = {0, 0, 0, 0, 0, 0, 0, 0};
#pragma unroll 4
  for (int k = 0; k < 256; ++k) {
    float bv = Gb[(size_t)k * 256];
#pragma unroll
    for (int o = 0; o < 8; ++o) acc[o] += Wcat[(r0 + o) * 256 + k] * bv;
  }
#pragma unroll
  for (int o = 0; o < 8; ++o)
    T12[(size_t)b * 131072 + (size_t)(r0 + o) * 256 + t] = acc[o];
  __shared__ float red[8][4];
  const int w = t >> 6, l = t & 63;
#pragma unroll
  for (int o = 0; o < 8; ++o) {
    float s = acc[o] * Wcat[(r0 + o) * 256 + t];
#pragma unroll
    for (int off = 32; off; off >>= 1) s += __shfl_xor(s, off);
    if (l == 0) red[o][w] = s;
  }
  __syncthreads();
  if (t < 8)
    nqk[b * 512 + r0 + t] = red[t][0] + red[t][1] + red[t][2] + red[t][3];
}

// ---- S = T1 @ Wk2^T fused with scaling + row-softmax -> attn ---------------
__global__ __launch_bounds__(256) void k_ssoft(const float* __restrict__ T12,
                                               const float* __restrict__ WkT,
                                               const float* __restrict__ nqk,
                                               const float* __restrict__ temp,
                                               float* __restrict__ attn) {
  const int t = threadIdx.x;
  const int c0 = blockIdx.x * 8, b = blockIdx.y;
  const float* Ab = T12 + (size_t)b * 131072 + (size_t)c0 * 256;  // T1 rows
  const float* Bb = WkT + t;
  float acc[8] = {0, 0, 0, 0, 0, 0, 0, 0};
#pragma unroll 4
  for (int k = 0; k < 256; ++k) {
    float bv = Bb[(size_t)k * 256];
#pragma unroll
    for (int o = 0; o < 8; ++o) acc[o] += Ab[o * 256 + k] * bv;
  }
  const float rk = 1.0f / fmaxf(sqrtf(fmaxf(nqk[b * 512 + 256 + t], 0.f)), 1e-12f);
  const float tau = temp[0];
#pragma unroll
  for (int o = 0; o < 8; ++o) {
    float rq = 1.0f / fmaxf(sqrtf(fmaxf(nqk[b * 512 + c0 + o], 0.f)), 1e-12f);
    acc[o] = acc[o] * rq * rk * tau;
  }
  __shared__ float redm[8][4];
  __shared__ float reds[8][4];
  const int w = t >> 6, l = t & 63;
#pragma unroll
  for (int o = 0; o < 8; ++o) {
    float m = acc[o];
#pragma unroll
    for (int off = 32; off; off >>= 1) m = fmaxf(m, __shfl_xor(m, off));
    if (l == 0) redm[o][w] = m;
  }
  __syncthreads();
  float e[8];
#pragma unroll
  for (int o = 0; o < 8; ++o) {
    float m = fmaxf(fmaxf(redm[o][0], redm[o][1]), fmaxf(redm[o][2], redm[o][3]));
    e[o] = __expf(acc[o] - m);
    float s = e[o];
#pragma unroll
    for (int off = 32; off; off >>= 1) s += __shfl_xor(s, off);
    if (l == 0) reds[o][w] = s;
  }
  __syncthreads();
#pragma unroll
  for (int o = 0; o < 8; ++o) {
    float tot = reds[o][0] + reds[o][1] + reds[o][2] + reds[o][3];
    attn[(size_t)b * 65536 + (size_t)(c0 + o) * 256 + t] = e[o] / tot;
  }
}

// ---- fused F = (Wp @ attn) @ Wv2, bf16 out ---------------------------------
__global__ __launch_bounds__(256) void k_sg2x(const float* __restrict__ wp,
                                              const float* __restrict__ attn,
                                              const float* __restrict__ wv2,
                                              char* __restrict__ Fb) {
  __shared__ float P[8 * 256];
  const int t = threadIdx.x;
  const int o0 = blockIdx.x * 8, b = blockIdx.y;
  const float* Ab = wp + (size_t)o0 * 256;
  const float* Bb = attn + (size_t)b * 65536 + t;
  float acc[8] = {0, 0, 0, 0, 0, 0, 0, 0};
#pragma unroll 4
  for (int k = 0; k < 256; ++k) {
    float bv = Bb[(size_t)k * 256];
#pragma unroll
    for (int o = 0; o < 8; ++o) acc[o] += Ab[o * 256 + k] * bv;
  }
#pragma unroll
  for (int o = 0; o < 8; ++o) P[o * 256 + t] = acc[o];
  __syncthreads();
  float a2[8] = {0, 0, 0, 0, 0, 0, 0, 0};
  const float* Bv = wv2 + t;
#pragma unroll 4
  for (int k = 0; k < 256; ++k) {
    float bv = Bv[(size_t)k * 256];
#pragma unroll
    for (int o = 0; o < 8; ++o) a2[o] += P[o * 256 + k] * bv;
  }
  unsigned short* Cp = (unsigned short*)Fb + (size_t)b * 65536;
#pragma unroll
  for (int o = 0; o < 8; ++o) Cp[(size_t)(o0 + o) * 256 + t] = f2bf(a2[o]);
}

// ---- final: out[b][o][n] = F[b] @ x[b]; outT tiles, T3-min 2-phase pipeline.
// Dbuf staging (2 x 32KB halves of the 64KB smem): STAGE(t+1) is issued
// BEFORE the ds_read+MFMA of tile t, so the loads fly during compute and the
// single vmcnt(0)+barrier per tile no longer exposes full stage latency
// (catalog T3 minimum, m248v2: 1.10x). Epilogue bounce reuses all 64KB.
__global__ __launch_bounds__(256) void k_final(const char* __restrict__ xt,
                                               const char* __restrict__ fb,
                                               float* __restrict__ out) {
  __shared__ char smem[65536];
  const int tid = threadIdx.x;
  const int nt = blockIdx.x, ot = blockIdx.y, b = blockIdx.z;
  const int w = tid >> 6, l = tid & 63;
  const int wm = w >> 1, wn = w & 1;
  f32x4 acc[4][4];
#pragma unroll
  for (int m = 0; m < 4; ++m)
#pragma unroll
    for (int nq = 0; nq < 4; ++nq) acc[m][nq] = (f32x4){0.f, 0.f, 0.f, 0.f};
  const char* Ap = xt + ((size_t)b * NN + (size_t)nt * 128) * 512;
  const char* Bp = fb + ((size_t)(b * 256 + ot * 128)) * 512;

  // prologue: stage ktile 0 into buf0
  stage_tile(Ap, 512, smem, w, l);
  stage_tile(Bp, 512, smem + 16384, w, l);
  __syncthreads();
  for (int kt = 0; kt < 4; ++kt) {
    // issue next tile's stage FIRST (into the other buffer)
    if (kt < 3) {
      char* nb = smem + ((kt + 1) & 1) * 32768;
      stage_tile(Ap + (kt + 1) * 128, 512, nb, w, l);
      stage_tile(Bp + (kt + 1) * 128, 512, nb + 16384, w, l);
    }
    // compute current tile (ds_read + MFMA) while next-tile loads fly
    const char* As = smem + (kt & 1) * 32768;
    const char* Bs = As + 16384;
#pragma unroll
    for (int ks = 0; ks < 2; ++ks) {
      bf16x8 av[4], bv[4];
      const int kb = ks * 64 + ((l >> 4) << 4);
#pragma unroll
      for (int m = 0; m < 4; ++m) {
        int row = wm * 64 + m * 16 + (l & 15);
        av[m] = *(const bf16x8*)(As + row * 128 + (kb ^ ((row & 7) << 4)));
      }
#pragma unroll
      for (int nq = 0; nq < 4; ++nq) {
        int row = wn * 64 + nq * 16 + (l & 15);
        bv[nq] = *(const bf16x8*)(Bs + row * 128 + (kb ^ ((row & 7) << 4)));
      }
#pragma unroll
      for (int m = 0; m < 4; ++m)
#pragma unroll
        for (int nq = 0; nq < 4; ++nq)
          acc[m][nq] = __builtin_amdgcn_mfma_f32_16x16x32_bf16(
              av[m], bv[nq], acc[m][nq], 0, 0, 0);
    }
    __syncthreads();   // one vmcnt(0)+barrier per tile; next buf now ready
  }
  // epilogue: bounce transposed into LDS [o_local 128][n_local 128], swizzled
#pragma unroll
  for (int m = 0; m < 4; ++m)
#pragma unroll
    for (int nq = 0; nq < 4; ++nq)
#pragma unroll
      for (int r = 0; r < 4; ++r) {
        int i = wm * 64 + m * 16 + ((l >> 4) << 2) + r;  // n_local (A row)
        int j = wn * 64 + nq * 16 + (l & 15);            // o_local (B row)
        *(float*)(smem + j * 512 + ((i * 4) ^ ((j & 7) << 4))) = acc[m][nq][r];
      }
  __syncthreads();
  const int j = tid >> 1, h = tid & 1;
  float* dst = out + ((size_t)(b * 256 + ot * 128 + j)) * NN + nt * 128;
#pragma unroll
  for (int cc = 0; cc < 16; ++cc) {
    int ch = h * 16 + cc;
    *(uint4*)(dst + ch * 4) =
        *(const uint4*)(smem + j * 512 + ((ch * 16) ^ ((j & 7) << 4)));
  }
}

extern "C" void kernel_launch(void* const* d_in, const int* in_sizes, int n_in,
                              void* d_out, int out_size, void* d_ws, size_t ws_size,
                              hipStream_t stream) {
  const float* x     = (const float*)d_in[0];
  const float* wqkv  = (const float*)d_in[1];
  const float* wdwf  = (const float*)d_in[2];
  const float* temp  = (const float*)d_in[3];
  const float* wproj = (const float*)d_in[4];
  float* out = (float*)d_out;
  char* ws = (char*)d_ws;

  // Workspace layout (bytes); total ~145 MB
  char*  xt    = ws;                            // bf16 [B][N][C]      67,108,864
  unsigned short* gpart = (unsigned short*)(ws + 67108864);
                                                // bf16 [64][B][256][256] 67,108,864
  float* G     = (float*)(ws + 134217728);      // f32 [B][256][256]    2,097,152
  float* T12   = (float*)(ws + 136314880);      // f32 [B][512][256]    4,194,304
  float* attn  = (float*)(ws + 140509184);      // f32 [B][256][256]    2,097,152
  char*  Fb    = ws + 142606336;                // bf16 [B][256][256]   1,048,576
  float* Wcat  = (float*)(ws + 143654912);      // f32 [512][256]         524,288
  float* WkT   = (float*)(ws + 144179200);      // f32 [256][256]         262,144
  float* Wv2   = (float*)(ws + 144441344);      // f32 [256][256]         262,144
  float* nqk   = (float*)(ws + 144703488);      // f32 [B][512]            16,384

  // fused gram + transpose-convert + weight-prep (role-split, 640 blocks)
  k_gramT<<<dim3(KS * NB + 128), dim3(512), 0, stream>>>(
      x, gpart, xt, wqkv, wdwf, Wcat, WkT, Wv2);
  k_reduceG<<<dim3(128, NB), dim3(256), 0, stream>>>(gpart, G);
  k_sgT<<<dim3(64, NB), dim3(256), 0, stream>>>(Wcat, G, T12, nqk);
  k_ssoft<<<dim3(32, NB), dim3(256), 0, stream>>>(T12, WkT, nqk, temp, attn);
  k_sg2x<<<dim3(32, NB), dim3(256), 0, stream>>>(wproj, attn, Wv2, Fb);
  k_final<<<dim3(128, 2, NB), dim3(256), 0, stream>>>(xt, Fb, out);
}

// Round 17
// 232.353 us; speedup vs baseline: 1.8575x; 1.0607x over previous
//
#include <hip/hip_runtime.h>
#include <hip/hip_bf16.h>
#include <stdint.h>

// Problem constants
#define NB 8
#define NC 256
#define NN 16384
#define KS 32        // gram k-split: 32 chunks of 512 (8 ktiles of 64)

typedef short bf16x8 __attribute__((ext_vector_type(8)));  // 8 bf16 = 4 VGPR
typedef float f32x4  __attribute__((ext_vector_type(4)));
typedef uint32_t u32;

__device__ __forceinline__ unsigned short f2bf(float f) {
  union { float f; unsigned u; } c; c.f = f;
  return (unsigned short)((c.u + 0x7FFFu + ((c.u >> 16) & 1u)) >> 16);  // RNE
}
__device__ __forceinline__ float bf2f(unsigned short h) {
  union { unsigned u; float f; } c; c.u = ((unsigned)h) << 16;
  return c.f;
}
// pack float2 -> 2 bf16 in a u32 (RNE, same rounding as f2bf)
__device__ __forceinline__ u32 pk2(float a, float b) {
  union { __hip_bfloat162 h; u32 u; } c;
  c.h = __float22bfloat162_rn(make_float2(a, b));
  return c.u;
}

// async global->LDS, 16B per lane; LDS dest is wave-uniform base + lane*16
__device__ __forceinline__ void gload16(const void* g, void* l) {
  __builtin_amdgcn_global_load_lds(
      (const __attribute__((address_space(1))) u32*)g,
      (__attribute__((address_space(3))) u32*)l, 16, 0, 0);
}

// Stage a [128 rows x 64 bf16] tile (row stride ld_bytes) into 16KB of LDS.
// T2 XOR-swizzle applied on the per-lane global source; LDS stays linear.
__device__ __forceinline__ void stage_tile(const char* src, int ld_bytes,
                                           char* lds, int w, int l) {
#pragma unroll
  for (int i = 0; i < 4; ++i) {
    int s = (w * 4 + i) * 64 + l;      // 0..1023 : 16B chunk index
    int row = s >> 3;
    int srcslot = (l & 7) ^ (row & 7);
    gload16(src + (size_t)row * ld_bytes + srcslot * 16,
            lds + (w * 4 + i) * 1024);
  }
}

// ---- gramT v4: reg-staged bf16 tile, fused gram + transpose + prepw --------
// blocks [0,256): gram role, one (ks,b) each, 1024 threads = 16 waves (4m x 4n).
// Per ktile (64 n-cols of the 512-wide K-chunk):
//   - each thread loads 4 float4 = x[c0..c0+3][n0..n0+3] (coalesced 256B runs)
//   - cvt ONCE to bf16 (8 pk2), ds_write_b64 into tile[256][72] (pad-144B rows
//     -> <=2-way bank aliasing on writes AND fragment reads, no XOR needed)
//   - MFMA: one ds_read_b128 per fragment, zero cvt (vs r16: 2 reads + 4 cvt)
//   - xt written straight from the bf16 regs (transpose LDS phase deleted)
//   - T14 async: loads(t+1) issued before MFMA(t); cvt(t+1) after -> HBM
//     latency hides under compute.
// blocks [256,320): weight prep (4 rows per block).
__global__ __launch_bounds__(1024) void k_gramT(
    const float* __restrict__ x, unsigned short* __restrict__ gpart,
    char* __restrict__ xt,
    const float* __restrict__ wqkv, const float* __restrict__ wdw,
    float* __restrict__ Wcat, float* __restrict__ WkT,
    float* __restrict__ Wv2) {
  __shared__ __align__(16) unsigned short tile[256 * 72];  // 36 KB
  const int bid = blockIdx.x;
  const int tid = threadIdx.x;

  if (bid >= KS * NB) {
    // ---------------- prepw role ----------------
    const int r = (bid - KS * NB) * 4 + (tid >> 8);
    const int t = tid & 255;
    Wcat[r * 256 + t] = wqkv[r * 256 + t] * wdw[r];
    float kv = wqkv[(256 + r) * 256 + t] * wdw[256 + r];
    Wcat[65536 + r * 256 + t] = kv;
    WkT[t * 256 + r] = kv;
    Wv2[r * 256 + t] = wqkv[(512 + r) * 256 + t] * wdw[512 + r];
    return;
  }

  // ---------------- gram role ----------------
  const int ks = bid & (KS - 1), b = bid >> 5;
  const int w = tid >> 6, l = tid & 63;
  const int wm = w >> 2, wn = w & 3;           // 4m x 4n wave grid
  const int cg = tid >> 4, ng = tid & 15;      // staging: c0=cg*4, n0=ng*4
  const int c0 = cg * 4, n0 = ng * 4;
  f32x4 acc[4][4];
#pragma unroll
  for (int m = 0; m < 4; ++m)
#pragma unroll
    for (int n = 0; n < 4; ++n) acc[m][n] = (f32x4){0.f, 0.f, 0.f, 0.f};
  const float* x0 = x + (size_t)b * NC * NN + (size_t)ks * 512;

  float4 f[4];     // fp32 staging (one generation)
  u32 hw[4][2];    // bf16 staging: hw[j] = 4 bf16 of row c0+j, cols n0..n0+3

#define LOADS(kt)                                                           \
  {                                                                         \
    _Pragma("unroll") for (int j = 0; j < 4; ++j)                           \
        f[j] = *(const float4*)&x0[(size_t)(c0 + j) * NN + (kt) * 64 + n0]; \
  }
#define CVT()                                                               \
  {                                                                         \
    _Pragma("unroll") for (int j = 0; j < 4; ++j) {                         \
      hw[j][0] = pk2(f[j].x, f[j].y);                                       \
      hw[j][1] = pk2(f[j].z, f[j].w);                                       \
    }                                                                       \
  }
#define DSW()                                                               \
  {                                                                         \
    _Pragma("unroll") for (int j = 0; j < 4; ++j)                           \
        *(uint2*)&tile[(c0 + j) * 72 + n0] = make_uint2(hw[j][0], hw[j][1]);\
  }

  // prologue: tile 0
  LOADS(0); CVT(); DSW();
  __syncthreads();

  for (int kt = 0; kt < 8; ++kt) {
    if (kt < 7) LOADS(kt + 1);   // issue next loads; land in regs during MFMA
    // ---- MFMA from bf16 tile (one b128 read per fragment) ----
#pragma unroll
    for (int ks2 = 0; ks2 < 2; ++ks2) {
      const int ko = ks2 * 32 + (l >> 4) * 8;   // elem offset of lane's 8 bf16
      bf16x8 av[4], bv[4];
#pragma unroll
      for (int m = 0; m < 4; ++m) {
        int row = wm * 64 + m * 16 + (l & 15);
        av[m] = *(const bf16x8*)&tile[row * 72 + ko];
      }
#pragma unroll
      for (int n = 0; n < 4; ++n) {
        int row = wn * 64 + n * 16 + (l & 15);
        bv[n] = *(const bf16x8*)&tile[row * 72 + ko];
      }
#pragma unroll
      for (int m = 0; m < 4; ++m)
#pragma unroll
        for (int n = 0; n < 4; ++n)
          acc[m][n] = __builtin_amdgcn_mfma_f32_16x16x32_bf16(
              av[m], bv[n], acc[m][n], 0, 0, 0);
    }
    // ---- xt[b][n][c] straight from bf16 regs (4 n-rows, 4 c each) ----
    {
      const int gn = ks * 512 + kt * 64 + n0;
#pragma unroll
      for (int k = 0; k < 4; ++k) {
        u32 e0 = (k < 2) ? (hw[0][0] >> (16 * k)) : (hw[0][1] >> (16 * (k - 2)));
        u32 e1 = (k < 2) ? (hw[1][0] >> (16 * k)) : (hw[1][1] >> (16 * (k - 2)));
        u32 e2 = (k < 2) ? (hw[2][0] >> (16 * k)) : (hw[2][1] >> (16 * (k - 2)));
        u32 e3 = (k < 2) ? (hw[3][0] >> (16 * k)) : (hw[3][1] >> (16 * (k - 2)));
        uint2 ov = make_uint2((e0 & 0xffff) | (e1 << 16),
                              (e2 & 0xffff) | (e3 << 16));
        *(uint2*)(xt + (((size_t)b * NN + gn + k) * 256 + c0) * 2) = ov;
      }
    }
    __syncthreads();             // tile consumed; safe to overwrite
    if (kt < 7) {
      CVT();                     // vmcnt for LOADS(kt+1) waits here (hidden)
      DSW();
      __syncthreads();           // tile(kt+1) ready
    }
  }
#undef LOADS
#undef CVT
#undef DSW
  // ---- gpart epilogue (bf16) ----
  unsigned short* gp = gpart + ((size_t)(ks * NB + b)) * 65536;
#pragma unroll
  for (int m = 0; m < 4; ++m)
#pragma unroll
    for (int n = 0; n < 4; ++n)
#pragma unroll
      for (int r = 0; r < 4; ++r) {
        int c = wm * 64 + m * 16 + ((l >> 4) << 2) + r;
        int d = wn * 64 + n * 16 + (l & 15);
        gp[(size_t)c * 256 + d] = f2bf(acc[m][n][r]);
      }
}

// ---- G[b] = sum_ks gpart (bf16 in, fp32 out); grid (128, NB) ---------------
__global__ __launch_bounds__(256) void k_reduceG(
    const unsigned short* __restrict__ gpart, float* __restrict__ G) {
  const int t = threadIdx.x;
  const int c = blockIdx.x * 2 + (t >> 7), b = blockIdx.y;
  const int d0 = (t & 127) * 2;
  float s0 = 0.f, s1 = 0.f;
#pragma unroll 8
  for (int ks = 0; ks < KS; ++ks) {
    u32 v = *(const u32*)(gpart + (((size_t)ks * NB + b) * 256 + c) * 256 + d0);
    s0 += bf2f((unsigned short)(v & 0xffff));
    s1 += bf2f((unsigned short)(v >> 16));
  }
  *(float2*)(G + ((size_t)b * 256 + c) * 256 + d0) = make_float2(s0, s1);
}

// ---- T12 = Wcat @ G, fused with norms: nqk[b][r] = dot(T12[b][r], Wcat[r]) -
__global__ __launch_bounds__(256) void k_sgT(const float* __restrict__ Wcat,
                                             const float* __restrict__ G,
                                             float* __restrict__ T12,
                                             float* __restrict__ nqk) {
  const int t = threadIdx.x;
  const int r0 = blockIdx.x * 8, b = blockIdx.y;
  const float* Gb = G + (size_t)b * 65536 + t;
  float acc[8] = {0, 0, 0, 0, 0, 0, 0, 0};
#pragma unroll 4
  for (int k = 0; k < 256; ++k) {
    float bv = Gb[(size_t)k * 256];
#pragma unroll
    for (int o = 0; o < 8; ++o) acc[o] += Wcat[(r0 + o) * 256 + k] * bv;
  }
#pragma unroll
  for (int o = 0; o < 8; ++o)
    T12[(size_t)b * 131072 + (size_t)(r0 + o) * 256 + t] = acc[o];
  __shared__ float red[8][4];
  const int w = t >> 6, l = t & 63;
#pragma unroll
  for (int o = 0; o < 8; ++o) {
    float s = acc[o] * Wcat[(r0 + o) * 256 + t];
#pragma unroll
    for (int off = 32; off; off >>= 1) s += __shfl_xor(s, off);
    if (l == 0) red[o][w] = s;
  }
  __syncthreads();
  if (t < 8)
    nqk[b * 512 + r0 + t] = red[t][0] + red[t][1] + red[t][2] + red[t][3];
}

// ---- S = T1 @ Wk2^T fused with scaling + row-softmax -> attn ---------------
__global__ __launch_bounds__(256) void k_ssoft(const float* __restrict__ T12,
                                               const float* __restrict__ WkT,
                                               const float* __restrict__ nqk,
                                               const float* __restrict__ temp,
                                               float* __restrict__ attn) {
  const int t = threadIdx.x;
  const int c0 = blockIdx.x * 8, b = blockIdx.y;
  const float* Ab = T12 + (size_t)b * 131072 + (size_t)c0 * 256;  // T1 rows
  const float* Bb = WkT + t;
  float acc[8] = {0, 0, 0, 0, 0, 0, 0, 0};
#pragma unroll 4
  for (int k = 0; k < 256; ++k) {
    float bv = Bb[(size_t)k * 256];
#pragma unroll
    for (int o = 0; o < 8; ++o) acc[o] += Ab[o * 256 + k] * bv;
  }
  const float rk = 1.0f / fmaxf(sqrtf(fmaxf(nqk[b * 512 + 256 + t], 0.f)), 1e-12f);
  const float tau = temp[0];
#pragma unroll
  for (int o = 0; o < 8; ++o) {
    float rq = 1.0f / fmaxf(sqrtf(fmaxf(nqk[b * 512 + c0 + o], 0.f)), 1e-12f);
    acc[o] = acc[o] * rq * rk * tau;
  }
  __shared__ float redm[8][4];
  __shared__ float reds[8][4];
  const int w = t >> 6, l = t & 63;
#pragma unroll
  for (int o = 0; o < 8; ++o) {
    float m = acc[o];
#pragma unroll
    for (int off = 32; off; off >>= 1) m = fmaxf(m, __shfl_xor(m, off));
    if (l == 0) redm[o][w] = m;
  }
  __syncthreads();
  float e[8];
#pragma unroll
  for (int o = 0; o < 8; ++o) {
    float m = fmaxf(fmaxf(redm[o][0], redm[o][1]), fmaxf(redm[o][2], redm[o][3]));
    e[o] = __expf(acc[o] - m);
    float s = e[o];
#pragma unroll
    for (int off = 32; off; off >>= 1) s += __shfl_xor(s, off);
    if (l == 0) reds[o][w] = s;
  }
  __syncthreads();
#pragma unroll
  for (int o = 0; o < 8; ++o) {
    float tot = reds[o][0] + reds[o][1] + reds[o][2] + reds[o][3];
    attn[(size_t)b * 65536 + (size_t)(c0 + o) * 256 + t] = e[o] / tot;
  }
}

// ---- fused F = (Wp @ attn) @ Wv2, bf16 out ---------------------------------
__global__ __launch_bounds__(256) void k_sg2x(const float* __restrict__ wp,
                                              const float* __restrict__ attn,
                                              const float* __restrict__ wv2,
                                              char* __restrict__ Fb) {
  __shared__ float P[8 * 256];
  const int t = threadIdx.x;
  const int o0 = blockIdx.x * 8, b = blockIdx.y;
  const float* Ab = wp + (size_t)o0 * 256;
  const float* Bb = attn + (size_t)b * 65536 + t;
  float acc[8] = {0, 0, 0, 0, 0, 0, 0, 0};
#pragma unroll 4
  for (int k = 0; k < 256; ++k) {
    float bv = Bb[(size_t)k * 256];
#pragma unroll
    for (int o = 0; o < 8; ++o) acc[o] += Ab[o * 256 + k] * bv;
  }
#pragma unroll
  for (int o = 0; o < 8; ++o) P[o * 256 + t] = acc[o];
  __syncthreads();
  float a2[8] = {0, 0, 0, 0, 0, 0, 0, 0};
  const float* Bv = wv2 + t;
#pragma unroll 4
  for (int k = 0; k < 256; ++k) {
    float bv = Bv[(size_t)k * 256];
#pragma unroll
    for (int o = 0; o < 8; ++o) a2[o] += P[o * 256 + k] * bv;
  }
  unsigned short* Cp = (unsigned short*)Fb + (size_t)b * 65536;
#pragma unroll
  for (int o = 0; o < 8; ++o) Cp[(size_t)(o0 + o) * 256 + t] = f2bf(a2[o]);
}

// ---- final: out[b][o][n] = F[b] @ x[b]; outT tiles, 2-phase pipeline -------
__global__ __launch_bounds__(256) void k_final(const char* __restrict__ xt,
                                               const char* __restrict__ fb,
                                               float* __restrict__ out) {
  __shared__ char smem[65536];
  const int tid = threadIdx.x;
  const int nt = blockIdx.x, ot = blockIdx.y, b = blockIdx.z;
  const int w = tid >> 6, l = tid & 63;
  const int wm = w >> 1, wn = w & 1;
  f32x4 acc[4][4];
#pragma unroll
  for (int m = 0; m < 4; ++m)
#pragma unroll
    for (int nq = 0; nq < 4; ++nq) acc[m][nq] = (f32x4){0.f, 0.f, 0.f, 0.f};
  const char* Ap = xt + ((size_t)b * NN + (size_t)nt * 128) * 512;
  const char* Bp = fb + ((size_t)(b * 256 + ot * 128)) * 512;

  stage_tile(Ap, 512, smem, w, l);
  stage_tile(Bp, 512, smem + 16384, w, l);
  __syncthreads();
  for (int kt = 0; kt < 4; ++kt) {
    if (kt < 3) {
      char* nb = smem + ((kt + 1) & 1) * 32768;
      stage_tile(Ap + (kt + 1) * 128, 512, nb, w, l);
      stage_tile(Bp + (kt + 1) * 128, 512, nb + 16384, w, l);
    }
    const char* As = smem + (kt & 1) * 32768;
    const char* Bs = As + 16384;
#pragma unroll
    for (int ks = 0; ks < 2; ++ks) {
      bf16x8 av[4], bv[4];
      const int kb = ks * 64 + ((l >> 4) << 4);
#pragma unroll
      for (int m = 0; m < 4; ++m) {
        int row = wm * 64 + m * 16 + (l & 15);
        av[m] = *(const bf16x8*)(As + row * 128 + (kb ^ ((row & 7) << 4)));
      }
#pragma unroll
      for (int nq = 0; nq < 4; ++nq) {
        int row = wn * 64 + nq * 16 + (l & 15);
        bv[nq] = *(const bf16x8*)(Bs + row * 128 + (kb ^ ((row & 7) << 4)));
      }
#pragma unroll
      for (int m = 0; m < 4; ++m)
#pragma unroll
        for (int nq = 0; nq < 4; ++nq)
          acc[m][nq] = __builtin_amdgcn_mfma_f32_16x16x32_bf16(
              av[m], bv[nq], acc[m][nq], 0, 0, 0);
    }
    __syncthreads();
  }
  // epilogue: bounce transposed into LDS [o_local 128][n_local 128], swizzled
#pragma unroll
  for (int m = 0; m < 4; ++m)
#pragma unroll
    for (int nq = 0; nq < 4; ++nq)
#pragma unroll
      for (int r = 0; r < 4; ++r) {
        int i = wm * 64 + m * 16 + ((l >> 4) << 2) + r;  // n_local (A row)
        int j = wn * 64 + nq * 16 + (l & 15);            // o_local (B row)
        *(float*)(smem + j * 512 + ((i * 4) ^ ((j & 7) << 4))) = acc[m][nq][r];
      }
  __syncthreads();
  const int j = tid >> 1, h = tid & 1;
  float* dst = out + ((size_t)(b * 256 + ot * 128 + j)) * NN + nt * 128;
#pragma unroll
  for (int cc = 0; cc < 16; ++cc) {
    int ch = h * 16 + cc;
    *(uint4*)(dst + ch * 4) =
        *(const uint4*)(smem + j * 512 + ((ch * 16) ^ ((j & 7) << 4)));
  }
}

extern "C" void kernel_launch(void* const* d_in, const int* in_sizes, int n_in,
                              void* d_out, int out_size, void* d_ws, size_t ws_size,
                              hipStream_t stream) {
  const float* x     = (const float*)d_in[0];
  const float* wqkv  = (const float*)d_in[1];
  const float* wdwf  = (const float*)d_in[2];
  const float* temp  = (const float*)d_in[3];
  const float* wproj = (const float*)d_in[4];
  float* out = (float*)d_out;
  char* ws = (char*)d_ws;

  // Workspace layout (bytes); total ~112 MB
  char*  xt    = ws;                            // bf16 [B][N][C]      67,108,864
  unsigned short* gpart = (unsigned short*)(ws + 67108864);
                                                // bf16 [32][B][256][256] 33,554,432
  float* G     = (float*)(ws + 100663296);      // f32 [B][256][256]    2,097,152
  float* T12   = (float*)(ws + 102760448);      // f32 [B][512][256]    4,194,304
  float* attn  = (float*)(ws + 106954752);      // f32 [B][256][256]    2,097,152
  char*  Fb    = ws + 109051904;                // bf16 [B][256][256]   1,048,576
  float* Wcat  = (float*)(ws + 110100480);      // f32 [512][256]         524,288
  float* WkT   = (float*)(ws + 110624768);      // f32 [256][256]         262,144
  float* Wv2   = (float*)(ws + 110886912);      // f32 [256][256]         262,144
  float* nqk   = (float*)(ws + 111149056);      // f32 [B][512]            16,384

  // fused gram + transpose-convert + weight-prep (320 blocks x 1024 thr)
  k_gramT<<<dim3(KS * NB + 64), dim3(1024), 0, stream>>>(
      x, gpart, xt, wqkv, wdwf, Wcat, WkT, Wv2);
  k_reduceG<<<dim3(128, NB), dim3(256), 0, stream>>>(gpart, G);
  k_sgT<<<dim3(64, NB), dim3(256), 0, stream>>>(Wcat, G, T12, nqk);
  k_ssoft<<<dim3(32, NB), dim3(256), 0, stream>>>(T12, WkT, nqk, temp, attn);
  k_sg2x<<<dim3(32, NB), dim3(256), 0, stream>>>(wproj, attn, Wv2, Fb);
  k_final<<<dim3(128, 2, NB), dim3(256), 0, stream>>>(xt, Fb, out);
}